// Round 5
// baseline (389.654 us; speedup 1.0000x reference)
//
#include <hip/hip_runtime.h>
#include <stdint.h>

// UKF (affine motion => exact Kalman filter). Inputs fp32, outputs fp32.
// Two-pass: pass 1 computes the recursion (1 wave/CU, parallelism pinned by
// B/64) and writes b-contiguous ws[f][tb][b][4] (perfectly coalesced);
// pass 2 (22 waves/CU) reorders ws -> (B, field, S), completing each 64B
// line in 4 back-to-back stores so L2 write-combines to full sectors.
// R4 evidence: direct kernel had WRITE_SIZE 288 MB == 2.0x amplification.

static constexpr float DTc = 0.1f;

// ---------------- Pass 1: compute, write ws (b-innermost) ----------------
__global__ __launch_bounds__(64) void ukf_compute_ws(
    const float* __restrict__ meas,   // (B, 2, S)
    const float* __restrict__ stin,   // (B, 4)
    const float* __restrict__ covin,  // (B, 4, 4)
    const float* __restrict__ ctrl,   // (B, S, 2)
    const float* __restrict__ Qp,     // (4,4)
    const float* __restrict__ Rp,     // (2,2)
    float4* __restrict__ ws,          // [22][NT][B] float4
    int B, int S)
{
    const int b = blockIdx.x * 64 + threadIdx.x;
    if (b >= B) return;

    float4 s4 = *reinterpret_cast<const float4*>(stin + (size_t)b * 4);
    float x0 = s4.x, x1 = s4.y, x2 = s4.z, x3 = s4.w;

    float p00, p01, p02, p03, p11, p12, p13, p22, p23, p33;
    {
        const float4* pc = reinterpret_cast<const float4*>(covin + (size_t)b * 16);
        float4 r0 = pc[0], r1 = pc[1], r2 = pc[2], r3 = pc[3];
        p00 = r0.x; p01 = r0.y; p02 = r0.z; p03 = r0.w;
        p11 = r1.y; p12 = r1.z; p13 = r1.w;
        p22 = r2.z; p23 = r2.w;
        p33 = r3.w;
    }
    float q00, q01, q02, q03, q11, q12, q13, q22, q23, q33;
    {
        const float4* pq = reinterpret_cast<const float4*>(Qp);
        float4 r0 = pq[0], r1 = pq[1], r2 = pq[2], r3 = pq[3];
        q00 = r0.x; q01 = r0.y; q02 = r0.z; q03 = r0.w;
        q11 = r1.y; q12 = r1.z; q13 = r1.w;
        q22 = r2.z; q23 = r2.w;
        q33 = r3.w;
    }
    float R00, R01, R10, R11;
    {
        float4 r = *reinterpret_cast<const float4*>(Rp);
        R00 = r.x; R01 = r.y; R10 = r.z; R11 = r.w;
    }

    const float4* pm0 = reinterpret_cast<const float4*>(meas + (size_t)b * 2 * S);
    const float4* pm1 = reinterpret_cast<const float4*>(meas + (size_t)b * 2 * S + S);
    const float4* pu  = reinterpret_cast<const float4*>(ctrl + (size_t)b * S * 2);

    const int NT = S / 4;
    const size_t fs = (size_t)NT * B;   // field stride in float4s

    float4 m0 = pm0[0], m1 = pm1[0], u0 = pu[0], u1 = pu[1];

    for (int tb = 0; tb < NT; ++tb) {
        float4 nm0 = make_float4(0, 0, 0, 0), nm1 = nm0, nu0 = nm0, nu1 = nm0;
        if (tb + 1 < NT) {
            nm0 = pm0[tb + 1];
            nm1 = pm1[tb + 1];
            nu0 = pu[2 * tb + 2];
            nu1 = pu[2 * tb + 3];
        }

        const float zb0[4] = { m0.x, m0.y, m0.z, m0.w };
        const float zb1[4] = { m1.x, m1.y, m1.z, m1.w };
        const float uxb[4] = { u0.x, u0.z, u1.x, u1.z };
        const float uyb[4] = { u0.y, u0.w, u1.y, u1.w };

        float pr[2][4];
        float st[4][4];
        float cb[16][4];

#pragma unroll
        for (int k = 0; k < 4; ++k) {
            const float ux = uxb[k], uy = uyb[k];

            const float xp0 = x0 + DTc * x2 + 0.5f * ux * DTc * DTc;
            const float xp1 = x1 + DTc * x3 + 0.5f * uy * DTc * DTc;
            const float xp2 = x2 + DTc * ux;
            const float xp3 = x3 + DTc * uy;

            const float FP00 = p00 + DTc * p02;
            const float FP01 = p01 + DTc * p12;
            const float FP02 = p02 + DTc * p22;
            const float FP03 = p03 + DTc * p23;
            const float FP11 = p11 + DTc * p13;
            const float FP12 = p12 + DTc * p23;
            const float FP13 = p13 + DTc * p33;

            const float a00 = FP00 + DTc * FP02;
            const float a01 = FP01 + DTc * FP03;
            const float a02 = FP02;
            const float a03 = FP03;
            const float a11 = FP11 + DTc * FP13;
            const float a12 = FP12;
            const float a13 = FP13;
            const float a22 = p22;
            const float a23 = p23;
            const float a33 = p33;

            const float s00 = a00 + R00, s01 = a01 + R01;
            const float s10 = a01 + R10, s11 = a11 + R11;
            const float rdet = 1.0f / (s00 * s11 - s01 * s10);
            const float i00 =  s11 * rdet, i01 = -s01 * rdet;
            const float i10 = -s10 * rdet, i11 =  s00 * rdet;

            const float K00 = a00 * i00 + a01 * i10;
            const float K01 = a00 * i01 + a01 * i11;
            const float K10 = a01 * i00 + a11 * i10;
            const float K11 = a01 * i01 + a11 * i11;
            const float K20 = a02 * i00 + a12 * i10;
            const float K21 = a02 * i01 + a12 * i11;
            const float K30 = a03 * i00 + a13 * i10;
            const float K31 = a03 * i01 + a13 * i11;

            const float in0 = zb0[k] - xp0;
            const float in1 = zb1[k] - xp1;
            const float xn0 = xp0 + K00 * in0 + K01 * in1;
            const float xn1 = xp1 + K10 * in0 + K11 * in1;
            const float xn2 = xp2 + K20 * in0 + K21 * in1;
            const float xn3 = xp3 + K30 * in0 + K31 * in1;

            const float M00 = K00 * s00 + K01 * s10;
            const float M01 = K00 * s01 + K01 * s11;
            const float M10 = K10 * s00 + K11 * s10;
            const float M11 = K10 * s01 + K11 * s11;
            const float M20 = K20 * s00 + K21 * s10;
            const float M21 = K20 * s01 + K21 * s11;
            const float M30 = K30 * s00 + K31 * s10;
            const float M31 = K30 * s01 + K31 * s11;

            p00 = (a00 + q00) - (M00 * K00 + M01 * K01);
            p01 = (a01 + q01) - (M00 * K10 + M01 * K11);
            p02 = (a02 + q02) - (M00 * K20 + M01 * K21);
            p03 = (a03 + q03) - (M00 * K30 + M01 * K31);
            p11 = (a11 + q11) - (M10 * K10 + M11 * K11);
            p12 = (a12 + q12) - (M10 * K20 + M11 * K21);
            p13 = (a13 + q13) - (M10 * K30 + M11 * K31);
            p22 = (a22 + q22) - (M20 * K20 + M21 * K21);
            p23 = (a23 + q23) - (M20 * K30 + M21 * K31);
            p33 = (a33 + q33) - (M30 * K30 + M31 * K31);

            x0 = xn0; x1 = xn1; x2 = xn2; x3 = xn3;

            pr[0][k] = xp0; pr[1][k] = xp1;
            st[0][k] = xn0; st[1][k] = xn1; st[2][k] = xn2; st[3][k] = xn3;

            cb[ 0][k] = p00; cb[ 1][k] = p01; cb[ 2][k] = p02; cb[ 3][k] = p03;
            cb[ 4][k] = p01; cb[ 5][k] = p11; cb[ 6][k] = p12; cb[ 7][k] = p13;
            cb[ 8][k] = p02; cb[ 9][k] = p12; cb[10][k] = p22; cb[11][k] = p23;
            cb[12][k] = p03; cb[13][k] = p13; cb[14][k] = p23; cb[15][k] = p33;
        }

        // ws[f][tb][b]: 64 lanes contiguous -> 1024 B per store instr
        float4* w = ws + (size_t)tb * B + b;
        w[0 * fs] = *reinterpret_cast<float4*>(pr[0]);
        w[1 * fs] = *reinterpret_cast<float4*>(pr[1]);
#pragma unroll
        for (int j = 0; j < 4; j++)
            w[(2 + j) * fs] = *reinterpret_cast<float4*>(st[j]);
#pragma unroll
        for (int r = 0; r < 16; r++)
            w[(6 + r) * fs] = *reinterpret_cast<float4*>(cb[r]);

        m0 = nm0; m1 = nm1; u0 = nu0; u1 = nu1;
    }
}

// ---------------- Pass 2: reorder ws -> (B, field, S) ----------------
__global__ __launch_bounds__(256) void ukf_scatter(
    const float4* __restrict__ ws,    // [22][NT][B] float4
    float* __restrict__ out,          // preds (B,2,S) | states (B,4,S) | covs (B,16,S)
    int B, int S)
{
    const int NT = S / 4;
    const int gid = blockIdx.x * 256 + threadIdx.x;   // f-major, b-innermost
    const int f = gid / B;            // wave-uniform (B multiple of 64)
    const int b = gid - f * B;

    const float4* src = ws + (size_t)f * NT * B + b;

    float* dst;
    if (f < 2)      dst = out + ((size_t)b * 2 + f) * S;
    else if (f < 6) dst = out + (size_t)B * 2 * S + ((size_t)b * 4 + (f - 2)) * S;
    else            dst = out + (size_t)B * 6 * S + ((size_t)b * 16 + (f - 6)) * S;
    float4* dst4 = reinterpret_cast<float4*>(dst);

    // reads: lane-contiguous (coalesced). writes: 16B strided across lanes,
    // but each lane completes its 64B lines in back-to-back iterations ->
    // L2 write-combines to full sectors.
#pragma unroll 5
    for (int tb = 0; tb < NT; ++tb)
        dst4[tb] = src[(size_t)tb * B];
}

// ---------------- Fallback: proven direct single-pass (R4) ----------------
__global__ __launch_bounds__(64) void ukf_kf_direct(
    const float* __restrict__ meas, const float* __restrict__ stin,
    const float* __restrict__ covin, const float* __restrict__ ctrl,
    const float* __restrict__ Qp, const float* __restrict__ Rp,
    float* __restrict__ out, int B, int S)
{
    const int b = blockIdx.x * 64 + threadIdx.x;
    if (b >= B) return;

    float4 s4 = *reinterpret_cast<const float4*>(stin + (size_t)b * 4);
    float x0 = s4.x, x1 = s4.y, x2 = s4.z, x3 = s4.w;
    float p00, p01, p02, p03, p11, p12, p13, p22, p23, p33;
    {
        const float4* pc = reinterpret_cast<const float4*>(covin + (size_t)b * 16);
        float4 r0 = pc[0], r1 = pc[1], r2 = pc[2], r3 = pc[3];
        p00 = r0.x; p01 = r0.y; p02 = r0.z; p03 = r0.w;
        p11 = r1.y; p12 = r1.z; p13 = r1.w; p22 = r2.z; p23 = r2.w; p33 = r3.w;
    }
    float q00, q01, q02, q03, q11, q12, q13, q22, q23, q33;
    {
        const float4* pq = reinterpret_cast<const float4*>(Qp);
        float4 r0 = pq[0], r1 = pq[1], r2 = pq[2], r3 = pq[3];
        q00 = r0.x; q01 = r0.y; q02 = r0.z; q03 = r0.w;
        q11 = r1.y; q12 = r1.z; q13 = r1.w; q22 = r2.z; q23 = r2.w; q33 = r3.w;
    }
    float R00, R01, R10, R11;
    {
        float4 r = *reinterpret_cast<const float4*>(Rp);
        R00 = r.x; R01 = r.y; R10 = r.z; R11 = r.w;
    }
    const float4* pm0 = reinterpret_cast<const float4*>(meas + (size_t)b * 2 * S);
    const float4* pm1 = reinterpret_cast<const float4*>(meas + (size_t)b * 2 * S + S);
    const float4* pu  = reinterpret_cast<const float4*>(ctrl + (size_t)b * S * 2);
    float* preds  = out + (size_t)b * 2 * S;
    float* states = out + (size_t)B * 2 * S + (size_t)b * 4 * S;
    float* covs   = out + (size_t)B * 6 * S + (size_t)b * 16 * S;
    const int NT = S / 4;
    float4 m0 = pm0[0], m1 = pm1[0], u0 = pu[0], u1 = pu[1];
    for (int tb = 0; tb < NT; ++tb) {
        float4 nm0 = make_float4(0,0,0,0), nm1 = nm0, nu0 = nm0, nu1 = nm0;
        if (tb + 1 < NT) { nm0 = pm0[tb+1]; nm1 = pm1[tb+1]; nu0 = pu[2*tb+2]; nu1 = pu[2*tb+3]; }
        const float zb0[4] = { m0.x, m0.y, m0.z, m0.w };
        const float zb1[4] = { m1.x, m1.y, m1.z, m1.w };
        const float uxb[4] = { u0.x, u0.z, u1.x, u1.z };
        const float uyb[4] = { u0.y, u0.w, u1.y, u1.w };
        float pr[2][4], st[4][4], cb[16][4];
#pragma unroll
        for (int k = 0; k < 4; ++k) {
            const float ux = uxb[k], uy = uyb[k];
            const float xp0 = x0 + DTc * x2 + 0.5f * ux * DTc * DTc;
            const float xp1 = x1 + DTc * x3 + 0.5f * uy * DTc * DTc;
            const float xp2 = x2 + DTc * ux;
            const float xp3 = x3 + DTc * uy;
            const float FP00 = p00 + DTc * p02, FP01 = p01 + DTc * p12;
            const float FP02 = p02 + DTc * p22, FP03 = p03 + DTc * p23;
            const float FP11 = p11 + DTc * p13, FP12 = p12 + DTc * p23, FP13 = p13 + DTc * p33;
            const float a00 = FP00 + DTc * FP02, a01 = FP01 + DTc * FP03;
            const float a02 = FP02, a03 = FP03;
            const float a11 = FP11 + DTc * FP13, a12 = FP12, a13 = FP13;
            const float a22 = p22, a23 = p23, a33 = p33;
            const float s00 = a00 + R00, s01 = a01 + R01;
            const float s10 = a01 + R10, s11 = a11 + R11;
            const float rdet = 1.0f / (s00 * s11 - s01 * s10);
            const float i00 =  s11 * rdet, i01 = -s01 * rdet;
            const float i10 = -s10 * rdet, i11 =  s00 * rdet;
            const float K00 = a00*i00 + a01*i10, K01 = a00*i01 + a01*i11;
            const float K10 = a01*i00 + a11*i10, K11 = a01*i01 + a11*i11;
            const float K20 = a02*i00 + a12*i10, K21 = a02*i01 + a12*i11;
            const float K30 = a03*i00 + a13*i10, K31 = a03*i01 + a13*i11;
            const float in0 = zb0[k] - xp0, in1 = zb1[k] - xp1;
            const float xn0 = xp0 + K00*in0 + K01*in1;
            const float xn1 = xp1 + K10*in0 + K11*in1;
            const float xn2 = xp2 + K20*in0 + K21*in1;
            const float xn3 = xp3 + K30*in0 + K31*in1;
            const float M00 = K00*s00 + K01*s10, M01 = K00*s01 + K01*s11;
            const float M10 = K10*s00 + K11*s10, M11 = K10*s01 + K11*s11;
            const float M20 = K20*s00 + K21*s10, M21 = K20*s01 + K21*s11;
            const float M30 = K30*s00 + K31*s10, M31 = K30*s01 + K31*s11;
            p00 = (a00+q00) - (M00*K00 + M01*K01);
            p01 = (a01+q01) - (M00*K10 + M01*K11);
            p02 = (a02+q02) - (M00*K20 + M01*K21);
            p03 = (a03+q03) - (M00*K30 + M01*K31);
            p11 = (a11+q11) - (M10*K10 + M11*K11);
            p12 = (a12+q12) - (M10*K20 + M11*K21);
            p13 = (a13+q13) - (M10*K30 + M11*K31);
            p22 = (a22+q22) - (M20*K20 + M21*K21);
            p23 = (a23+q23) - (M20*K30 + M21*K31);
            p33 = (a33+q33) - (M30*K30 + M31*K31);
            x0 = xn0; x1 = xn1; x2 = xn2; x3 = xn3;
            pr[0][k] = xp0; pr[1][k] = xp1;
            st[0][k] = xn0; st[1][k] = xn1; st[2][k] = xn2; st[3][k] = xn3;
            cb[ 0][k]=p00; cb[ 1][k]=p01; cb[ 2][k]=p02; cb[ 3][k]=p03;
            cb[ 4][k]=p01; cb[ 5][k]=p11; cb[ 6][k]=p12; cb[ 7][k]=p13;
            cb[ 8][k]=p02; cb[ 9][k]=p12; cb[10][k]=p22; cb[11][k]=p23;
            cb[12][k]=p03; cb[13][k]=p13; cb[14][k]=p23; cb[15][k]=p33;
        }
        const int t0 = tb * 4;
        *reinterpret_cast<float4*>(preds + t0)     = *reinterpret_cast<float4*>(pr[0]);
        *reinterpret_cast<float4*>(preds + S + t0) = *reinterpret_cast<float4*>(pr[1]);
#pragma unroll
        for (int j = 0; j < 4; j++)
            *reinterpret_cast<float4*>(states + j * S + t0) = *reinterpret_cast<float4*>(st[j]);
#pragma unroll
        for (int r = 0; r < 16; r++)
            *reinterpret_cast<float4*>(covs + r * S + t0) = *reinterpret_cast<float4*>(cb[r]);
        m0 = nm0; m1 = nm1; u0 = nu0; u1 = nu1;
    }
}

extern "C" void kernel_launch(void* const* d_in, const int* in_sizes, int n_in,
                              void* d_out, int out_size, void* d_ws, size_t ws_size,
                              hipStream_t stream) {
    // Identify inputs by element count (order-robust):
    int iR = -1, iQ = -1, iMeas = -1, iCtrl = -1, iState = -1, iCov = -1;
    for (int i = 0; i < n_in; i++) {
        if (in_sizes[i] == 4 && iR < 0) iR = i;
        else if (in_sizes[i] == 16 && iQ < 0) iQ = i;
    }
    for (int i = 0; i < n_in && iMeas < 0; i++) {
        if (i == iR || i == iQ) continue;
        for (int j = i + 1; j < n_in; j++) {
            if (j == iR || j == iQ) continue;
            if (in_sizes[i] == in_sizes[j]) { iMeas = i; iCtrl = j; break; }
        }
    }
    int rem[2], nrem = 0;
    for (int i = 0; i < n_in && nrem < 2; i++) {
        if (i == iR || i == iQ || i == iMeas || i == iCtrl) continue;
        rem[nrem++] = i;
    }
    if (in_sizes[rem[0]] > in_sizes[rem[1]]) { iCov = rem[0]; iState = rem[1]; }
    else                                     { iCov = rem[1]; iState = rem[0]; }

    const float* meas  = (const float*)d_in[iMeas];
    const float* stin  = (const float*)d_in[iState];
    const float* covin = (const float*)d_in[iCov];
    const float* ctrl  = (const float*)d_in[iCtrl];
    const float* Qp    = (const float*)d_in[iQ];
    const float* Rp    = (const float*)d_in[iR];
    float* out = (float*)d_out;

    const int B = in_sizes[iState] / 4;
    const int S = in_sizes[iMeas] / (2 * B);
    const int NT = S / 4;

    const size_t ws_needed = (size_t)22 * NT * B * 16;   // 137.5 MB at B=16384,S=100
    if (ws_size >= ws_needed && (B % 256) == 0) {
        float4* ws = (float4*)d_ws;
        ukf_compute_ws<<<dim3(B / 64), dim3(64), 0, stream>>>(
            meas, stin, covin, ctrl, Qp, Rp, ws, B, S);
        ukf_scatter<<<dim3(22 * B / 256), dim3(256), 0, stream>>>(ws, out, B, S);
    } else {
        ukf_kf_direct<<<dim3((B + 63) / 64), dim3(64), 0, stream>>>(
            meas, stin, covin, ctrl, Qp, Rp, out, B, S);
    }
}

// Round 6
// 238.245 us; speedup vs baseline: 1.6355x; 1.6355x over previous
//
#include <hip/hip_runtime.h>
#include <stdint.h>

// UKF (affine motion => exact Kalman filter; sigma machinery collapses to
// F P F^T exactly). Inputs fp32, outputs fp32 (proven R1-R4).
//
// R5 lesson: 16B partial-line stores cost ~2-2.8x HBM write amplification
// REGARDLESS of temporal adjacency (R5 scatter: 398MB for 144MB logical).
// Only wave-instruction-level contiguity is 1x. So: OCTET REDUNDANCY —
// 8 lanes per batch element all compute the same recursion (VALU was 96%
// idle), lane j stages the t-window [4j..4j+3) mod 32 of every output row
// in registers; each 32-step flush writes 128B contiguous per b per row
// (8 lanes x 16B in ONE instruction => full-sector coverage). Also lifts
// occupancy 1 -> 8 waves/CU (B*8 threads), fixing R4's latency ceiling.

static constexpr float DTc = 0.1f;

__global__ __launch_bounds__(256, 2) void ukf_oct(
    const float* __restrict__ meas,   // (B, 2, S)
    const float* __restrict__ stin,   // (B, 4)
    const float* __restrict__ covin,  // (B, 4, 4)
    const float* __restrict__ ctrl,   // (B, S, 2)
    const float* __restrict__ Qp,     // (4,4)
    const float* __restrict__ Rp,     // (2,2)
    float* __restrict__ out,          // preds (B,2,S) | states (B,4,S) | covs (B,4,4,S)
    int B, int S)
{
    const int tid = blockIdx.x * 256 + threadIdx.x;
    const int b   = tid >> 3;          // 8 lanes per batch element
    const int myj = tid & 7;           // my 4-step window within a 32-step tile
    if (b >= B) return;

    float4 s4 = *reinterpret_cast<const float4*>(stin + (size_t)b * 4);
    float x0 = s4.x, x1 = s4.y, x2 = s4.z, x3 = s4.w;

    float p00, p01, p02, p03, p11, p12, p13, p22, p23, p33;
    {
        const float4* pc = reinterpret_cast<const float4*>(covin + (size_t)b * 16);
        float4 r0 = pc[0], r1 = pc[1], r2 = pc[2], r3 = pc[3];
        p00 = r0.x; p01 = r0.y; p02 = r0.z; p03 = r0.w;
        p11 = r1.y; p12 = r1.z; p13 = r1.w; p22 = r2.z; p23 = r2.w; p33 = r3.w;
    }
    float q00, q01, q02, q03, q11, q12, q13, q22, q23, q33;
    {
        const float4* pq = reinterpret_cast<const float4*>(Qp);
        float4 r0 = pq[0], r1 = pq[1], r2 = pq[2], r3 = pq[3];
        q00 = r0.x; q01 = r0.y; q02 = r0.z; q03 = r0.w;
        q11 = r1.y; q12 = r1.z; q13 = r1.w; q22 = r2.z; q23 = r2.w; q33 = r3.w;
    }
    float R00, R01, R10, R11;
    {
        float4 r = *reinterpret_cast<const float4*>(Rp);
        R00 = r.x; R01 = r.y; R10 = r.z; R11 = r.w;
    }

    const float4* pm0 = reinterpret_cast<const float4*>(meas + (size_t)b * 2 * S);
    const float4* pm1 = reinterpret_cast<const float4*>(meas + (size_t)b * 2 * S + S);
    const float4* pu  = reinterpret_cast<const float4*>(ctrl + (size_t)b * S * 2);

    float* bp = out + (size_t)b * 2 * S;                       // preds rows
    float* bs = out + (size_t)B * 2 * S + (size_t)b * 4 * S;   // states rows
    float* bc = out + (size_t)B * 6 * S + (size_t)b * 16 * S;  // covs rows

    const int NT = S / 4;              // 4-step sub-tiles (25 for S=100)

    // staging: lane's 4-step window of {preds0,1, states0..3, P-triangle 0..9}
    float4 sgp0, sgp1, sgs0, sgs1, sgs2, sgs3;
    float4 sgt[10];

    float4 m0 = pm0[0], m1 = pm1[0], u0 = pu[0], u1 = pu[1];

    for (int sub = 0; sub < NT; ++sub) {
        float4 nm0 = make_float4(0, 0, 0, 0), nm1 = nm0, nu0 = nm0, nu1 = nm0;
        if (sub + 1 < NT) {
            nm0 = pm0[sub + 1];
            nm1 = pm1[sub + 1];
            nu0 = pu[2 * sub + 2];
            nu1 = pu[2 * sub + 3];
        }

        const float zb0[4] = { m0.x, m0.y, m0.z, m0.w };
        const float zb1[4] = { m1.x, m1.y, m1.z, m1.w };
        const float uxb[4] = { u0.x, u0.z, u1.x, u1.z };
        const float uyb[4] = { u0.y, u0.w, u1.y, u1.w };

        const bool take = ((sub & 7) == myj);

#pragma unroll
        for (int k = 0; k < 4; ++k) {
            const float ux = uxb[k], uy = uyb[k];

            const float xp0 = x0 + DTc * x2 + 0.5f * ux * DTc * DTc;
            const float xp1 = x1 + DTc * x3 + 0.5f * uy * DTc * DTc;
            const float xp2 = x2 + DTc * ux;
            const float xp3 = x3 + DTc * uy;

            const float FP00 = p00 + DTc * p02, FP01 = p01 + DTc * p12;
            const float FP02 = p02 + DTc * p22, FP03 = p03 + DTc * p23;
            const float FP11 = p11 + DTc * p13, FP12 = p12 + DTc * p23;
            const float FP13 = p13 + DTc * p33;

            const float a00 = FP00 + DTc * FP02, a01 = FP01 + DTc * FP03;
            const float a02 = FP02, a03 = FP03;
            const float a11 = FP11 + DTc * FP13, a12 = FP12, a13 = FP13;
            const float a22 = p22, a23 = p23, a33 = p33;

            const float s00 = a00 + R00, s01 = a01 + R01;
            const float s10 = a01 + R10, s11 = a11 + R11;
            const float rdet = 1.0f / (s00 * s11 - s01 * s10);
            const float i00 =  s11 * rdet, i01 = -s01 * rdet;
            const float i10 = -s10 * rdet, i11 =  s00 * rdet;

            const float K00 = a00*i00 + a01*i10, K01 = a00*i01 + a01*i11;
            const float K10 = a01*i00 + a11*i10, K11 = a01*i01 + a11*i11;
            const float K20 = a02*i00 + a12*i10, K21 = a02*i01 + a12*i11;
            const float K30 = a03*i00 + a13*i10, K31 = a03*i01 + a13*i11;

            const float in0 = zb0[k] - xp0, in1 = zb1[k] - xp1;
            const float xn0 = xp0 + K00*in0 + K01*in1;
            const float xn1 = xp1 + K10*in0 + K11*in1;
            const float xn2 = xp2 + K20*in0 + K21*in1;
            const float xn3 = xp3 + K30*in0 + K31*in1;

            const float M00 = K00*s00 + K01*s10, M01 = K00*s01 + K01*s11;
            const float M10 = K10*s00 + K11*s10, M11 = K10*s01 + K11*s11;
            const float M20 = K20*s00 + K21*s10, M21 = K20*s01 + K21*s11;
            const float M30 = K30*s00 + K31*s10, M31 = K30*s01 + K31*s11;

            p00 = (a00+q00) - (M00*K00 + M01*K01);
            p01 = (a01+q01) - (M00*K10 + M01*K11);
            p02 = (a02+q02) - (M00*K20 + M01*K21);
            p03 = (a03+q03) - (M00*K30 + M01*K31);
            p11 = (a11+q11) - (M10*K10 + M11*K11);
            p12 = (a12+q12) - (M10*K20 + M11*K21);
            p13 = (a13+q13) - (M10*K30 + M11*K31);
            p22 = (a22+q22) - (M20*K20 + M21*K21);
            p23 = (a23+q23) - (M20*K30 + M21*K31);
            p33 = (a33+q33) - (M30*K30 + M31*K31);

            x0 = xn0; x1 = xn1; x2 = xn2; x3 = xn3;

            if (take) {  // exec-masked register captures of this lane's window
                float* c0 = (k==0) ? &sgp0.x : (k==1) ? &sgp0.y : (k==2) ? &sgp0.z : &sgp0.w;
                // (compiler folds k at unroll; write each field explicitly)
                if (k == 0) {
                    sgp0.x=xp0; sgp1.x=xp1; sgs0.x=xn0; sgs1.x=xn1; sgs2.x=xn2; sgs3.x=xn3;
                    sgt[0].x=p00; sgt[1].x=p01; sgt[2].x=p02; sgt[3].x=p03; sgt[4].x=p11;
                    sgt[5].x=p12; sgt[6].x=p13; sgt[7].x=p22; sgt[8].x=p23; sgt[9].x=p33;
                } else if (k == 1) {
                    sgp0.y=xp0; sgp1.y=xp1; sgs0.y=xn0; sgs1.y=xn1; sgs2.y=xn2; sgs3.y=xn3;
                    sgt[0].y=p00; sgt[1].y=p01; sgt[2].y=p02; sgt[3].y=p03; sgt[4].y=p11;
                    sgt[5].y=p12; sgt[6].y=p13; sgt[7].y=p22; sgt[8].y=p23; sgt[9].y=p33;
                } else if (k == 2) {
                    sgp0.z=xp0; sgp1.z=xp1; sgs0.z=xn0; sgs1.z=xn1; sgs2.z=xn2; sgs3.z=xn3;
                    sgt[0].z=p00; sgt[1].z=p01; sgt[2].z=p02; sgt[3].z=p03; sgt[4].z=p11;
                    sgt[5].z=p12; sgt[6].z=p13; sgt[7].z=p22; sgt[8].z=p23; sgt[9].z=p33;
                } else {
                    sgp0.w=xp0; sgp1.w=xp1; sgs0.w=xn0; sgs1.w=xn1; sgs2.w=xn2; sgs3.w=xn3;
                    sgt[0].w=p00; sgt[1].w=p01; sgt[2].w=p02; sgt[3].w=p03; sgt[4].w=p11;
                    sgt[5].w=p12; sgt[6].w=p13; sgt[7].w=p22; sgt[8].w=p23; sgt[9].w=p33;
                }
                (void)c0;
            }
        }

        if ((sub & 7) == 7) {   // flush a 32-step tile: 128B contiguous per b per row
            const int off = (sub & ~7) * 4 + myj * 4;   // float offset in row
            *reinterpret_cast<float4*>(bp + 0 * S + off) = sgp0;
            *reinterpret_cast<float4*>(bp + 1 * S + off) = sgp1;
            *reinterpret_cast<float4*>(bs + 0 * S + off) = sgs0;
            *reinterpret_cast<float4*>(bs + 1 * S + off) = sgs1;
            *reinterpret_cast<float4*>(bs + 2 * S + off) = sgs2;
            *reinterpret_cast<float4*>(bs + 3 * S + off) = sgs3;
            // covs rows: mirror triangle -> 16 rows (row i*4+l -> tri index)
            const int map[16] = {0,1,2,3, 1,4,5,6, 2,5,7,8, 3,6,8,9};
#pragma unroll
            for (int r = 0; r < 16; r++)
                *reinterpret_cast<float4*>(bc + r * S + off) = sgt[map[r]];
        }

        m0 = nm0; m1 = nm1; u0 = nu0; u1 = nu1;
    }

    // tail: NT % 8 leftover sub-tiles (1 for S=100), staged by lanes myj < rem
    const int rem = NT & 7;
    if (rem && myj < rem) {
        const int off = (NT & ~7) * 4 + myj * 4;
        *reinterpret_cast<float4*>(bp + 0 * S + off) = sgp0;
        *reinterpret_cast<float4*>(bp + 1 * S + off) = sgp1;
        *reinterpret_cast<float4*>(bs + 0 * S + off) = sgs0;
        *reinterpret_cast<float4*>(bs + 1 * S + off) = sgs1;
        *reinterpret_cast<float4*>(bs + 2 * S + off) = sgs2;
        *reinterpret_cast<float4*>(bs + 3 * S + off) = sgs3;
        const int map[16] = {0,1,2,3, 1,4,5,6, 2,5,7,8, 3,6,8,9};
#pragma unroll
        for (int r = 0; r < 16; r++)
            *reinterpret_cast<float4*>(bc + r * S + off) = sgt[map[r]];
    }
}

extern "C" void kernel_launch(void* const* d_in, const int* in_sizes, int n_in,
                              void* d_out, int out_size, void* d_ws, size_t ws_size,
                              hipStream_t stream) {
    // Identify inputs by element count (order-robust):
    int iR = -1, iQ = -1, iMeas = -1, iCtrl = -1, iState = -1, iCov = -1;
    for (int i = 0; i < n_in; i++) {
        if (in_sizes[i] == 4 && iR < 0) iR = i;
        else if (in_sizes[i] == 16 && iQ < 0) iQ = i;
    }
    for (int i = 0; i < n_in && iMeas < 0; i++) {
        if (i == iR || i == iQ) continue;
        for (int j = i + 1; j < n_in; j++) {
            if (j == iR || j == iQ) continue;
            if (in_sizes[i] == in_sizes[j]) { iMeas = i; iCtrl = j; break; }
        }
    }
    int rem[2], nrem = 0;
    for (int i = 0; i < n_in && nrem < 2; i++) {
        if (i == iR || i == iQ || i == iMeas || i == iCtrl) continue;
        rem[nrem++] = i;
    }
    if (in_sizes[rem[0]] > in_sizes[rem[1]]) { iCov = rem[0]; iState = rem[1]; }
    else                                     { iCov = rem[1]; iState = rem[0]; }

    const float* meas  = (const float*)d_in[iMeas];
    const float* stin  = (const float*)d_in[iState];
    const float* covin = (const float*)d_in[iCov];
    const float* ctrl  = (const float*)d_in[iCtrl];
    const float* Qp    = (const float*)d_in[iQ];
    const float* Rp    = (const float*)d_in[iR];
    float* out = (float*)d_out;

    const int B = in_sizes[iState] / 4;
    const int S = in_sizes[iMeas] / (2 * B);

    // 8 threads per batch element, 256-thread blocks
    const int total = B * 8;
    ukf_oct<<<dim3((total + 255) / 256), dim3(256), 0, stream>>>(
        meas, stin, covin, ctrl, Qp, Rp, out, B, S);
}